// Round 1
// baseline (700.670 us; speedup 1.0000x reference)
//
#include <hip/hip_runtime.h>
#include <hip/hip_bf16.h>

// CapsModel: B=64 N=32 H=W=16 A=16 K=3 stride=2 -> Ho=Wo=7, M=32, SD=4, D=16
// Stage 1: conv capsule routing per site (b,h,w): 3136 sites
// Stage 2: FC capsule routing per b: Nfc=1568, Cls=10

#define LN_EPS 1e-5f

// ---------------- Stage 1: conv routing ----------------
// grid: 3136 blocks (b*49 + h*7 + w), block: 256 threads = 32 m-lanes x 8 groups
// Each group handles 36 of the 288 (n,k,l) input capsules.
__global__ __launch_bounds__(256) void conv_routing_kernel(
    const float* __restrict__ x,      // [64][32][16][16][16]
    const float* __restrict__ wconv,  // [3][3][32][4][4][32] (k,l,n,x,d,m)
    const float* __restrict__ ln1g,
    const float* __restrict__ ln1b,
    const int*   __restrict__ nroute,
    float* __restrict__ vout)         // [64][32][49][16]
{
    __shared__ float s_inp[288][16];     // inp[nkl][a*4+x]
    __shared__ float s_v[32][16];        // current v per m (post-LN)
    __shared__ float s_red[8][32][16];   // per-group partials

    const int site = blockIdx.x;
    const int b  = site / 49;
    const int hw = site % 49;
    const int h  = hw / 7, w = hw % 7;
    const int tid = threadIdx.x;
    const int m = tid & 31;
    const int g = tid >> 5;

    // Load inp slice: inp[n,k,l,a,x] = x[b,n,2h+k,2w+l,a*4+x]
    for (int i = tid; i < 288 * 16; i += 256) {
        const int row = i >> 4, col = i & 15;
        const int n = row / 9, kl = row % 9;
        const int k = kl / 3, l = kl % 3;
        s_inp[row][col] =
            x[(((b * 32 + n) * 16 + (2 * h + k)) * 16 + (2 * w + l)) * 16 + col];
    }
    __syncthreads();

    const int R = *nroute;

    for (int pass = 0; pass < R; ++pass) {
        float vnew[16];
#pragma unroll
        for (int i = 0; i < 16; ++i) vnew[i] = 0.f;

        for (int t = 0; t < 36; ++t) {
            const int nkl = g + t * 8;
            const int n = nkl / 9, kl = nkl % 9;
            const int k = kl / 3, l = kl % 3;
            // w_conv[k][l][n][x][d][m], this lane's m; xd index = x*4+d
            const float* wp = wconv + (((k * 3 + l) * 32 + n) * 16) * 32 + m;
            float wv[16];
#pragma unroll
            for (int xd = 0; xd < 16; ++xd) wv[xd] = wp[xd * 32];

            // uh[a*4+d] = sum_x inp[a,x]*w[x,d]
            float uh[16];
#pragma unroll
            for (int a = 0; a < 4; ++a) {
#pragma unroll
                for (int d = 0; d < 4; ++d) {
                    float s = 0.f;
#pragma unroll
                    for (int xx = 0; xx < 4; ++xx)
                        s += s_inp[nkl][a * 4 + xx] * wv[xx * 4 + d];
                    uh[a * 4 + d] = s;
                }
            }

            if (pass == 0) {
#pragma unroll
                for (int i = 0; i < 16; ++i) vnew[i] += uh[i];
            } else {
                float lg = 0.f;
#pragma unroll
                for (int i = 0; i < 16; ++i) lg += uh[i] * s_v[m][i];
                lg *= 0.25f;
                // softmax over m = 32 lanes (butterfly within 32-lane partition)
                float mx = lg;
#pragma unroll
                for (int off = 16; off >= 1; off >>= 1)
                    mx = fmaxf(mx, __shfl_xor(mx, off, 32));
                const float e = __expf(lg - mx);
                float sm = e;
#pragma unroll
                for (int off = 16; off >= 1; off >>= 1)
                    sm += __shfl_xor(sm, off, 32);
                // qk = softmax / (sum_m softmax + 1e-10) = e/sm / (1+1e-10)
                const float qk = e / (sm * (1.f + 1e-10f));
#pragma unroll
                for (int i = 0; i < 16; ++i) vnew[i] += qk * uh[i];
            }
        }

        // reduce partials across the 8 groups
#pragma unroll
        for (int i = 0; i < 16; ++i) s_red[g][m][i] = vnew[i];
        __syncthreads();

        // LayerNorm per m over the 16 (a,d) values; one thread per m
        if (tid < 32) {
            float vv[16];
            const float scale = (pass == 0) ? (1.f / 32.f) : 1.f;
            float mu = 0.f;
#pragma unroll
            for (int i = 0; i < 16; ++i) {
                float s = 0.f;
#pragma unroll
                for (int gg = 0; gg < 8; ++gg) s += s_red[gg][tid][i];
                s *= scale;
                vv[i] = s;
                mu += s;
            }
            mu *= (1.f / 16.f);
            float var = 0.f;
#pragma unroll
            for (int i = 0; i < 16; ++i) {
                const float d0 = vv[i] - mu;
                var += d0 * d0;
            }
            var *= (1.f / 16.f);
            const float inv = rsqrtf(var + LN_EPS);
#pragma unroll
            for (int i = 0; i < 16; ++i)
                s_v[tid][i] = (vv[i] - mu) * inv * ln1g[i] + ln1b[i];
        }
        __syncthreads();
    }

    // write v: vout[b][m][hw][ad]
    for (int p = tid; p < 512; p += 256) {
        const int mm = p >> 4, ad = p & 15;
        vout[((b * 32 + mm) * 49 + hw) * 16 + ad] = s_v[mm][ad];
    }
}

// ---------------- Stage 2: FC routing ----------------
// grid: 64 blocks (one per b), block: 256 threads = 16 ad-lanes x 16 groups.
// Each group handles 98 of the 1568 n's.
__global__ __launch_bounds__(256) void fc_routing_kernel(
    const float* __restrict__ fcin,  // [64][1568][16]  (b, n=(m*7+h)*7+w, D)
    const float* __restrict__ wfc,   // [1568][4][4][10] (n,x,d,m)
    const float* __restrict__ ln2g,
    const float* __restrict__ ln2b,
    const int*   __restrict__ nroute,
    float* __restrict__ out)         // [64][10][16]
{
    __shared__ float s_u[10][16];
    __shared__ float s_red[16][10][16];

    const int b = blockIdx.x;
    const int tid = threadIdx.x;
    const int ad = tid & 15;
    const int g  = tid >> 4;
    const int a = ad >> 2, d = ad & 3;

    const int R = *nroute;
    const float* fb = fcin + b * 1568 * 16;

    for (int pass = 0; pass < R; ++pass) {
        float unew[10];
#pragma unroll
        for (int i = 0; i < 10; ++i) unew[i] = 0.f;

        for (int t = 0; t < 98; ++t) {
            const int n = g + t * 16;
            float in4[4];
#pragma unroll
            for (int xx = 0; xx < 4; ++xx) in4[xx] = fb[n * 16 + a * 4 + xx];

            // vote[m] = sum_x in[a,x] * wfc[n,x,d,m]  (this lane's a,d)
            float vote[10];
#pragma unroll
            for (int mm = 0; mm < 10; ++mm) {
                float s = 0.f;
#pragma unroll
                for (int xx = 0; xx < 4; ++xx)
                    s += in4[xx] * wfc[((n * 4 + xx) * 4 + d) * 10 + mm];
                vote[mm] = s;
            }

            if (pass == 0) {
#pragma unroll
                for (int mm = 0; mm < 10; ++mm) unew[mm] += vote[mm];
            } else {
                // logits[m] = 0.25 * sum_{ad} vote[m]*u[m][ad]; reduce over 16 lanes
                float lg[10];
#pragma unroll
                for (int mm = 0; mm < 10; ++mm) lg[mm] = vote[mm] * s_u[mm][ad];
#pragma unroll
                for (int off = 8; off >= 1; off >>= 1) {
#pragma unroll
                    for (int mm = 0; mm < 10; ++mm)
                        lg[mm] += __shfl_xor(lg[mm], off, 16);
                }
                float mx = -1e30f;
#pragma unroll
                for (int mm = 0; mm < 10; ++mm) {
                    lg[mm] *= 0.25f;
                    mx = fmaxf(mx, lg[mm]);
                }
                float e[10];
                float sm = 0.f;
#pragma unroll
                for (int mm = 0; mm < 10; ++mm) {
                    e[mm] = __expf(lg[mm] - mx);
                    sm += e[mm];
                }
                const float inv = 1.f / (sm * (1.f + 1e-10f));
#pragma unroll
                for (int mm = 0; mm < 10; ++mm) unew[mm] += e[mm] * inv * vote[mm];
            }
        }

        // reduce partials over 16 groups
#pragma unroll
        for (int mm = 0; mm < 10; ++mm) s_red[g][mm][ad] = unew[mm];
        __syncthreads();

        if (tid < 160) {
            const int mm = tid >> 4, aad = tid & 15;
            float s = 0.f;
#pragma unroll
            for (int gg = 0; gg < 16; ++gg) s += s_red[gg][mm][aad];
            if (pass == 0) s *= 0.1f;
            s_red[0][mm][aad] = s;
        }
        __syncthreads();

        // LayerNorm per m over 16
        if (tid < 10) {
            float vv[16];
            float mu = 0.f;
#pragma unroll
            for (int i = 0; i < 16; ++i) {
                vv[i] = s_red[0][tid][i];
                mu += vv[i];
            }
            mu *= (1.f / 16.f);
            float var = 0.f;
#pragma unroll
            for (int i = 0; i < 16; ++i) {
                const float d0 = vv[i] - mu;
                var += d0 * d0;
            }
            var *= (1.f / 16.f);
            const float inv = rsqrtf(var + LN_EPS);
#pragma unroll
            for (int i = 0; i < 16; ++i)
                s_u[tid][i] = (vv[i] - mu) * inv * ln2g[i] + ln2b[i];
        }
        __syncthreads();
    }

    for (int p = tid; p < 160; p += 256) {
        out[b * 160 + p] = s_u[p >> 4][p & 15];
    }
}

extern "C" void kernel_launch(void* const* d_in, const int* in_sizes, int n_in,
                              void* d_out, int out_size, void* d_ws, size_t ws_size,
                              hipStream_t stream) {
    const float* x     = (const float*)d_in[0];
    const float* wconv = (const float*)d_in[1];
    const float* wfc   = (const float*)d_in[2];
    const float* ln1g  = (const float*)d_in[3];
    const float* ln1b  = (const float*)d_in[4];
    const float* ln2g  = (const float*)d_in[5];
    const float* ln2b  = (const float*)d_in[6];
    const int*   nrt   = (const int*)d_in[7];

    float* vout = (float*)d_ws;  // 64*32*49*16 floats = 6.4 MB
    float* out  = (float*)d_out;

    hipLaunchKernelGGL(conv_routing_kernel, dim3(64 * 49), dim3(256), 0, stream,
                       x, wconv, ln1g, ln1b, nrt, vout);
    hipLaunchKernelGGL(fc_routing_kernel, dim3(64), dim3(256), 0, stream,
                       vout, wfc, ln2g, ln2b, nrt, out);
}

// Round 3
// 676.889 us; speedup vs baseline: 1.0351x; 1.0351x over previous
//
#include <hip/hip_runtime.h>
#include <hip/hip_bf16.h>

// CapsModel: B=64 N=32 H=W=16 A=16 K=3 stride=2 -> Ho=Wo=7, M=32, SD=4, D=16
// Stage 1: conv capsule routing, 2 sites per block, 1568 blocks.
// Stage 2: FC capsule routing, 1 block per b (1024 threads), 64 blocks.
// Weights pre-transposed into d_ws for vectorized coalesced loads.

#define LN_EPS 1e-5f

// ---------------- weight transpose ----------------
// wT  [288][32][16] : row r is N-MAJOR (r = n*9 + kl) to match s_inp ordering.
//   wT[(r*32+m)*16+xd] = wconv[((kl*32+n)*16+xd)*32+m]  (wconv row = (k*3+l)*32+n)
// wT2 [1568][4][4][10] (n,d,x,m) : wT2[((n*4+d)*4+x)*10+m] = wfc[((n*4+x)*4+d)*10+m]
__global__ __launch_bounds__(256) void transpose_weights(
    const float* __restrict__ wconv, const float* __restrict__ wfc,
    float* __restrict__ wT, float* __restrict__ wT2)
{
    const int i = blockIdx.x * 256 + threadIdx.x;
    if (i < 147456) {
        const int xd = i & 15, mm = (i >> 4) & 31, r = i >> 9;   // r = n*9+kl
        const int n = r / 9, kl = r % 9;
        wT[i] = wconv[((kl * 32 + n) * 16 + xd) * 32 + mm];
    } else {
        const int j = i - 147456;
        if (j < 250880) {
            const int mm = j % 10;
            const int r = j / 10;              // (n*4+d)*4+x
            const int x = r & 3, dd = (r >> 2) & 3, n = r >> 4;
            wT2[j] = wfc[((n * 4 + x) * 4 + dd) * 10 + mm];
        }
    }
}

// ---------------- Stage 1: conv routing ----------------
// block: 256 threads = 32 m-lanes x 8 groups; group g owns nkl in [g*36, g*36+36)
// 2 sites per block.
__global__ __launch_bounds__(256) void conv_routing_kernel(
    const float* __restrict__ x,      // [64][32][16][16][16]
    const float* __restrict__ wT,     // [288][32][16], row = n*9+kl
    const float* __restrict__ ln1g,
    const float* __restrict__ ln1b,
    const int*   __restrict__ nroute,
    float* __restrict__ vout)         // [64][32][49][16]
{
    __shared__ float s_inp[2][288][16];     // 36 KB, row = n*9+kl
    __shared__ float s_v[2][32][16];        // 4 KB
    __shared__ float s_red[2][4][32][17];   // 17 KB, stride-17 pad = conflict-free

    const int tid = threadIdx.x;
    const int m   = tid & 31;
    const int g   = tid >> 5;    // 0..7
    const int wvi = tid >> 6;    // wave 0..3
    const int site0 = blockIdx.x * 2;

    // stage inp for both sites (float4, coalesced)
    for (int i = tid; i < 2304; i += 256) {   // 2 * 288 * 4 float4
        const int s = (i >= 1152) ? 1 : 0;
        const int j = s ? i - 1152 : i;
        const int row = j >> 2, q = j & 3;
        const int site = site0 + s;
        const int b = site / 49, hw = site % 49;
        const int h = hw / 7, w = hw % 7;
        const int n = row / 9, kl = row % 9;
        const int k = kl / 3, l = kl % 3;
        const float4 val = *(const float4*)(
            x + ((((b * 32 + n) * 16 + (2 * h + k)) * 16 + (2 * w + l)) * 16 + q * 4));
        *(float4*)(&s_inp[s][row][q * 4]) = val;
    }
    __syncthreads();

    const int R = *nroute;
    const int nkl0 = g * 36;
    const float* const wp0 = wT + (nkl0 * 32 + m) * 16;

    for (int pass = 0; pass < R; ++pass) {
        float vn0[16], vn1[16];
#pragma unroll
        for (int i = 0; i < 16; ++i) { vn0[i] = 0.f; vn1[i] = 0.f; }
        float vc0[16], vc1[16];
        if (pass) {
#pragma unroll
            for (int i = 0; i < 16; ++i) { vc0[i] = s_v[0][m][i]; vc1[i] = s_v[1][m][i]; }
        }

        const float* wp = wp0;
        for (int t = 0; t < 36; ++t, wp += 512) {
            float wv_[16];
#pragma unroll
            for (int q = 0; q < 4; ++q)
                *(float4*)(&wv_[q * 4]) = *(const float4*)(wp + q * 4);
            const int nkl = nkl0 + t;

#pragma unroll
            for (int s = 0; s < 2; ++s) {
                float in_[16];
#pragma unroll
                for (int q = 0; q < 4; ++q)
                    *(float4*)(&in_[q * 4]) = *(const float4*)(&s_inp[s][nkl][q * 4]);
                float uh[16];
#pragma unroll
                for (int a = 0; a < 4; ++a) {
#pragma unroll
                    for (int d = 0; d < 4; ++d) {
                        float acc = in_[a * 4 + 0] * wv_[0 + d];
                        acc = fmaf(in_[a * 4 + 1], wv_[4 + d], acc);
                        acc = fmaf(in_[a * 4 + 2], wv_[8 + d], acc);
                        acc = fmaf(in_[a * 4 + 3], wv_[12 + d], acc);
                        uh[a * 4 + d] = acc;
                    }
                }
                float* vn = s ? vn1 : vn0;
                const float* vc = s ? vc1 : vc0;
                if (pass == 0) {
#pragma unroll
                    for (int i = 0; i < 16; ++i) vn[i] += uh[i];
                } else {
                    float lg = 0.f;
#pragma unroll
                    for (int i = 0; i < 16; ++i) lg = fmaf(uh[i], vc[i], lg);
                    lg *= 0.25f;
                    float mx = lg;
#pragma unroll
                    for (int off = 16; off >= 1; off >>= 1)
                        mx = fmaxf(mx, __shfl_xor(mx, off, 32));
                    const float e = __expf(lg - mx);
                    float sm = e;
#pragma unroll
                    for (int off = 16; off >= 1; off >>= 1)
                        sm += __shfl_xor(sm, off, 32);
                    const float qk = e * __builtin_amdgcn_rcpf(sm * (1.f + 1e-10f));
#pragma unroll
                    for (int i = 0; i < 16; ++i) vn[i] = fmaf(qk, uh[i], vn[i]);
                }
            }
        }

        // pre-reduce the 2 groups within each wave, then 4 partials to LDS
#pragma unroll
        for (int i = 0; i < 16; ++i) {
            vn0[i] += __shfl_xor(vn0[i], 32, 64);
            vn1[i] += __shfl_xor(vn1[i], 32, 64);
        }
        if ((tid & 32) == 0) {
#pragma unroll
            for (int i = 0; i < 16; ++i) {
                s_red[0][wvi][m][i] = vn0[i];
                s_red[1][wvi][m][i] = vn1[i];
            }
        }
        __syncthreads();

        // LayerNorm: 64 threads, (s, m)
        if (tid < 64) {
            const int s = tid >> 5, mm = tid & 31;
            const float scale = pass ? 1.f : (1.f / 32.f);
            float vv[16];
            float mu = 0.f;
#pragma unroll
            for (int i = 0; i < 16; ++i) {
                float ss = s_red[s][0][mm][i] + s_red[s][1][mm][i]
                         + s_red[s][2][mm][i] + s_red[s][3][mm][i];
                ss *= scale;
                vv[i] = ss;
                mu += ss;
            }
            mu *= (1.f / 16.f);
            float var = 0.f;
#pragma unroll
            for (int i = 0; i < 16; ++i) {
                const float d0 = vv[i] - mu;
                var = fmaf(d0, d0, var);
            }
            var *= (1.f / 16.f);
            const float inv = rsqrtf(var + LN_EPS);
#pragma unroll
            for (int i = 0; i < 16; ++i)
                s_v[s][mm][i] = (vv[i] - mu) * inv * ln1g[i] + ln1b[i];
        }
        __syncthreads();
    }

    // write v: 256 float4
    {
        const int p = tid;
        const int s = p >> 7, mm = (p >> 2) & 31, q = p & 3;
        const int site = site0 + s;
        const int b = site / 49, hw = site % 49;
        const float4 val = *(const float4*)(&s_v[s][mm][q * 4]);
        *(float4*)(vout + ((b * 32 + mm) * 49 + hw) * 16 + q * 4) = val;
    }
}

// ---------------- Stage 2: FC routing ----------------
// 64 blocks (one per b), 1024 threads = 64 groups x 16 ad-lanes.
__global__ __launch_bounds__(1024) void fc_routing_kernel(
    const float* __restrict__ fcin,  // [64][1568][16]  (n = (m*7+h)*7+w)
    const float* __restrict__ wT2,   // [1568][4(d)][4(x)][10(m)]
    const float* __restrict__ ln2g,
    const float* __restrict__ ln2b,
    const int*   __restrict__ nroute,
    float* __restrict__ out)         // [64][10][16]
{
    __shared__ float s_u[10][16];
    __shared__ float s_red[16][10][17];

    const int b   = blockIdx.x;
    const int tid = threadIdx.x;
    const int ad  = tid & 15;
    const int g   = tid >> 4;    // 0..63
    const int a = ad >> 2, d = ad & 3;
    const int wvi = tid >> 6;    // 0..15
    const int R = *nroute;
    const float* fb = fcin + b * 1568 * 16;

    for (int pass = 0; pass < R; ++pass) {
        float un[10];
#pragma unroll
        for (int mm = 0; mm < 10; ++mm) un[mm] = 0.f;
        float ur[10];
        if (pass) {
#pragma unroll
            for (int mm = 0; mm < 10; ++mm) ur[mm] = s_u[mm][ad];
        }

        for (int t = 0; t < 25; ++t) {
            const int n = g + t * 64;
            if (n >= 1568) break;   // wave-uniform (only waves 8..15 at t==24)
            float in4[4];
            *(float4*)in4 = *(const float4*)(fb + n * 16 + a * 4);
            const float* wpn = wT2 + (n * 16 + d * 4) * 10;
            float wrow[40];
#pragma unroll
            for (int q = 0; q < 10; ++q)
                *(float4*)(&wrow[q * 4]) = *(const float4*)(wpn + q * 4);
            float vote[10];
#pragma unroll
            for (int mm = 0; mm < 10; ++mm) {
                float s = in4[0] * wrow[0 + mm];
                s = fmaf(in4[1], wrow[10 + mm], s);
                s = fmaf(in4[2], wrow[20 + mm], s);
                s = fmaf(in4[3], wrow[30 + mm], s);
                vote[mm] = s;
            }

            if (pass == 0) {
#pragma unroll
                for (int mm = 0; mm < 10; ++mm) un[mm] += vote[mm];
            } else {
                float lg[10];
#pragma unroll
                for (int mm = 0; mm < 10; ++mm) lg[mm] = vote[mm] * ur[mm];
#pragma unroll
                for (int off = 8; off >= 1; off >>= 1) {
#pragma unroll
                    for (int mm = 0; mm < 10; ++mm)
                        lg[mm] += __shfl_xor(lg[mm], off, 16);
                }
                float mx = -1e30f;
#pragma unroll
                for (int mm = 0; mm < 10; ++mm) {
                    lg[mm] *= 0.25f;
                    mx = fmaxf(mx, lg[mm]);
                }
                float sm = 0.f;
                float e[10];
#pragma unroll
                for (int mm = 0; mm < 10; ++mm) {
                    e[mm] = __expf(lg[mm] - mx);
                    sm += e[mm];
                }
                const float inv = __builtin_amdgcn_rcpf(sm * (1.f + 1e-10f));
#pragma unroll
                for (int mm = 0; mm < 10; ++mm)
                    un[mm] = fmaf(e[mm] * inv, vote[mm], un[mm]);
            }
        }

        // pre-reduce 4 groups within each wave
#pragma unroll
        for (int mm = 0; mm < 10; ++mm) {
            un[mm] += __shfl_xor(un[mm], 16, 64);
            un[mm] += __shfl_xor(un[mm], 32, 64);
        }
        if ((tid & 63) < 16) {
#pragma unroll
            for (int mm = 0; mm < 10; ++mm) s_red[wvi][mm][ad] = un[mm];
        }
        __syncthreads();

        if (tid < 160) {
            const int mm = tid >> 4, aad = tid & 15;
            float sacc = 0.f;
#pragma unroll
            for (int wq = 0; wq < 16; ++wq) sacc += s_red[wq][mm][aad];
            if (pass == 0) sacc *= 0.1f;
            s_red[0][mm][aad] = sacc;   // own slot only: safe
        }
        __syncthreads();

        if (tid < 10) {
            float vv[16];
            float mu = 0.f;
#pragma unroll
            for (int i = 0; i < 16; ++i) { vv[i] = s_red[0][tid][i]; mu += vv[i]; }
            mu *= (1.f / 16.f);
            float var = 0.f;
#pragma unroll
            for (int i = 0; i < 16; ++i) {
                const float d0 = vv[i] - mu;
                var = fmaf(d0, d0, var);
            }
            var *= (1.f / 16.f);
            const float inv = rsqrtf(var + LN_EPS);
#pragma unroll
            for (int i = 0; i < 16; ++i)
                s_u[tid][i] = (vv[i] - mu) * inv * ln2g[i] + ln2b[i];
        }
        __syncthreads();
    }

    if (tid < 160) out[b * 160 + tid] = s_u[tid >> 4][tid & 15];
}

extern "C" void kernel_launch(void* const* d_in, const int* in_sizes, int n_in,
                              void* d_out, int out_size, void* d_ws, size_t ws_size,
                              hipStream_t stream) {
    const float* x     = (const float*)d_in[0];
    const float* wconv = (const float*)d_in[1];
    const float* wfc   = (const float*)d_in[2];
    const float* ln1g  = (const float*)d_in[3];
    const float* ln1b  = (const float*)d_in[4];
    const float* ln2g  = (const float*)d_in[5];
    const float* ln2b  = (const float*)d_in[6];
    const int*   nrt   = (const int*)d_in[7];

    float* vout = (float*)d_ws;                                   // 6,422,528 B
    float* wT   = (float*)((char*)d_ws + 6422528);                // 589,824 B
    float* wT2  = (float*)((char*)d_ws + 6422528 + 589824);       // 1,003,520 B
    float* out  = (float*)d_out;

    hipLaunchKernelGGL(transpose_weights, dim3(1556), dim3(256), 0, stream,
                       wconv, wfc, wT, wT2);
    hipLaunchKernelGGL(conv_routing_kernel, dim3(1568), dim3(256), 0, stream,
                       x, wT, ln1g, ln1b, nrt, vout);
    hipLaunchKernelGGL(fc_routing_kernel, dim3(64), dim3(1024), 0, stream,
                       vout, wT2, ln2g, ln2b, nrt, out);
}

// Round 4
// 506.431 us; speedup vs baseline: 1.3835x; 1.3366x over previous
//
#include <hip/hip_runtime.h>
#include <hip/hip_bf16.h>

// CapsModel: B=64 N=32 H=W=16 A=16 K=3 stride=2 -> Ho=Wo=7, M=32, SD=4, D=16
// conv routing: 2 sites/block, 1568 blocks, 256 thr (32 m-lanes x 8 nkl-groups)
// fc routing:   64 blocks, 1024 thr = 64 n-groups x 16 m-lanes
// No-max softmax (|logit| <~16, exp safe in fp32).

#define LN_EPS 1e-5f

// ---------------- weight transposes ----------------
// wT [288][32][16]: row r = n*9+kl (n-major, matches s_inp), wT[(r*32+m)*16+xd]
__global__ __launch_bounds__(256) void transpose_wconv(
    const float* __restrict__ wconv, float* __restrict__ wT)
{
    const int i = blockIdx.x * 256 + threadIdx.x;
    if (i < 147456) {
        const int xd = i & 15, mm = (i >> 4) & 31, r = i >> 9;   // r = n*9+kl
        const int n = r / 9, kl = r % 9;
        wT[i] = wconv[((kl * 32 + n) * 16 + xd) * 32 + mm];
    }
}

// wT2b [1568][16][16]: [n][m (pad 10->16, zeros)][x*4+d]
__global__ __launch_bounds__(256) void transpose_wfc(
    const float* __restrict__ wfc, float* __restrict__ wT2b)
{
    const int j = blockIdx.x * 256 + threadIdx.x;
    if (j < 401408) {
        const int xd = j & 15, mm = (j >> 4) & 15, n = j >> 8;
        const int x = xd >> 2, dd = xd & 3;
        wT2b[j] = (mm < 10) ? wfc[((n * 4 + x) * 4 + dd) * 10 + mm] : 0.f;
    }
}

// ---------------- Stage 1: conv routing ----------------
__global__ __launch_bounds__(256, 3) void conv_routing_kernel(
    const float* __restrict__ x,      // [64][32][16][16][16]
    const float* __restrict__ wT,     // [288][32][16], row = n*9+kl
    const float* __restrict__ ln1g,
    const float* __restrict__ ln1b,
    const int*   __restrict__ nroute,
    float* __restrict__ vout)         // [64][32][49][16]
{
    __shared__ float s_inp[2][288][16];     // 36 KB
    __shared__ float s_v[2][32][16];        // 4 KB
    __shared__ float s_red[3][2][32][16];   // 12 KB  (waves 1..3 partials)

    const int tid  = threadIdx.x;
    const int m    = tid & 31;
    const int g    = tid >> 5;     // 0..7
    const int wvi  = tid >> 6;     // 0..3
    const int hmask = tid & 32;    // 0 for lower half-wave
    const int site0 = blockIdx.x * 2;

    // stage inp for both sites (float4, coalesced); row = n*9+kl
    for (int i = tid; i < 2304; i += 256) {
        const int s = (i >= 1152) ? 1 : 0;
        const int j = s ? i - 1152 : i;
        const int row = j >> 2, q = j & 3;
        const int site = site0 + s;
        const int b = site / 49, hw = site % 49;
        const int h = hw / 7, w = hw % 7;
        const int n = row / 9, kl = row % 9;
        const int k = kl / 3, l = kl % 3;
        const float4 val = *(const float4*)(
            x + ((((b * 32 + n) * 16 + (2 * h + k)) * 16 + (2 * w + l)) * 16 + q * 4));
        *(float4*)(&s_inp[s][row][q * 4]) = val;
    }
    __syncthreads();

    const int R = *nroute;
    const int nkl0 = g * 36;
    const float* const wp0 = wT + (nkl0 * 32 + m) * 16;

#define LDW(dst, p)                                                  \
    {                                                                \
        _Pragma("unroll") for (int q = 0; q < 4; ++q)                \
            *(float4*)(&(dst)[q * 4]) = *(const float4*)((p) + q * 4); \
    }

    for (int pass = 0; pass < R; ++pass) {
        float vn0[16], vn1[16];
#pragma unroll
        for (int i = 0; i < 16; ++i) { vn0[i] = 0.f; vn1[i] = 0.f; }
        float vc0[16], vc1[16];
        if (pass) {
#pragma unroll
            for (int q = 0; q < 4; ++q) {
                *(float4*)(&vc0[q * 4]) = *(const float4*)(&s_v[0][m][q * 4]);
                *(float4*)(&vc1[q * 4]) = *(const float4*)(&s_v[1][m][q * 4]);
            }
        }

        // pass-0 body: pure accumulate
        auto body0 = [&](int t, const float* wv) {
            const int nkl = nkl0 + t;
#pragma unroll
            for (int s = 0; s < 2; ++s) {
                float in_[16];
#pragma unroll
                for (int q = 0; q < 4; ++q)
                    *(float4*)(&in_[q * 4]) = *(const float4*)(&s_inp[s][nkl][q * 4]);
                float* vn = s ? vn1 : vn0;
#pragma unroll
                for (int a = 0; a < 4; ++a) {
#pragma unroll
                    for (int d = 0; d < 4; ++d) {
                        float acc = in_[a * 4 + 0] * wv[0 + d];
                        acc = fmaf(in_[a * 4 + 1], wv[4 + d], acc);
                        acc = fmaf(in_[a * 4 + 2], wv[8 + d], acc);
                        acc = fmaf(in_[a * 4 + 3], wv[12 + d], acc);
                        vn[a * 4 + d] += acc;
                    }
                }
            }
        };

        // routing body: votes -> logit -> no-max softmax over 32 m-lanes -> accum
        auto body1 = [&](int t, const float* wv) {
            const int nkl = nkl0 + t;
#pragma unroll
            for (int s = 0; s < 2; ++s) {
                float in_[16];
#pragma unroll
                for (int q = 0; q < 4; ++q)
                    *(float4*)(&in_[q * 4]) = *(const float4*)(&s_inp[s][nkl][q * 4]);
                float uh[16];
#pragma unroll
                for (int a = 0; a < 4; ++a) {
#pragma unroll
                    for (int d = 0; d < 4; ++d) {
                        float acc = in_[a * 4 + 0] * wv[0 + d];
                        acc = fmaf(in_[a * 4 + 1], wv[4 + d], acc);
                        acc = fmaf(in_[a * 4 + 2], wv[8 + d], acc);
                        acc = fmaf(in_[a * 4 + 3], wv[12 + d], acc);
                        uh[a * 4 + d] = acc;
                    }
                }
                const float* vc = s ? vc1 : vc0;
                float* vn = s ? vn1 : vn0;
                float lg = 0.f;
#pragma unroll
                for (int i = 0; i < 16; ++i) lg = fmaf(uh[i], vc[i], lg);
                lg *= 0.25f;
                const float e = __expf(lg);
                float sm = e;
#pragma unroll
                for (int off = 16; off >= 1; off >>= 1)
                    sm += __shfl_xor(sm, off, 32);
                const float qk = e * __builtin_amdgcn_rcpf(sm * (1.f + 1e-10f));
#pragma unroll
                for (int i = 0; i < 16; ++i) vn[i] = fmaf(qk, uh[i], vn[i]);
            }
        };

        // K-loop, unroll 2 with double-buffered w prefetch
        {
            const float* wp = wp0;
            float wA[16], wB[16];
            LDW(wA, wp);
            if (pass == 0) {
                for (int t2 = 0; t2 < 18; ++t2) {
                    const int t = t2 * 2;
                    LDW(wB, wp + 512);
                    body0(t, wA);
                    if (t2 < 17) LDW(wA, wp + 1024);
                    body0(t + 1, wB);
                    wp += 1024;
                }
            } else {
                for (int t2 = 0; t2 < 18; ++t2) {
                    const int t = t2 * 2;
                    LDW(wB, wp + 512);
                    body1(t, wA);
                    if (t2 < 17) LDW(wA, wp + 1024);
                    body1(t + 1, wB);
                    wp += 1024;
                }
            }
        }

        // cross half-wave prereduce (both halves end with the total)
#pragma unroll
        for (int i = 0; i < 16; ++i) {
            vn0[i] += __shfl_xor(vn0[i], 32, 64);
            vn1[i] += __shfl_xor(vn1[i], 32, 64);
        }
        if (wvi > 0 && hmask == 0) {
#pragma unroll
            for (int q = 0; q < 4; ++q) {
                *(float4*)(&s_red[wvi - 1][0][m][q * 4]) = *(float4*)(&vn0[q * 4]);
                *(float4*)(&s_red[wvi - 1][1][m][q * 4]) = *(float4*)(&vn1[q * 4]);
            }
        }
        __syncthreads();

        if (wvi == 0 && hmask == 0) {
#pragma unroll
            for (int j = 0; j < 3; ++j) {
#pragma unroll
                for (int i = 0; i < 16; ++i) {
                    vn0[i] += s_red[j][0][m][i];
                    vn1[i] += s_red[j][1][m][i];
                }
            }
            const float scale = pass ? 1.f : (1.f / 32.f);
#pragma unroll
            for (int s = 0; s < 2; ++s) {
                float* vv = s ? vn1 : vn0;
                float mu = 0.f;
#pragma unroll
                for (int i = 0; i < 16; ++i) { vv[i] *= scale; mu += vv[i]; }
                mu *= (1.f / 16.f);
                float var = 0.f;
#pragma unroll
                for (int i = 0; i < 16; ++i) {
                    const float d0 = vv[i] - mu;
                    var = fmaf(d0, d0, var);
                }
                var *= (1.f / 16.f);
                const float inv = rsqrtf(var + LN_EPS);
#pragma unroll
                for (int i = 0; i < 16; ++i)
                    s_v[s][m][i] = (vv[i] - mu) * inv * ln1g[i] + ln1b[i];
            }
        }
        __syncthreads();
    }

    // write v: 256 float4
    {
        const int p = tid;
        const int s = p >> 7, mm = (p >> 2) & 31, q = p & 3;
        const int site = site0 + s;
        const int b = site / 49, hw = site % 49;
        const float4 val = *(const float4*)(&s_v[s][mm][q * 4]);
        *(float4*)(vout + ((b * 32 + mm) * 49 + hw) * 16 + q * 4) = val;
    }
}

// ---------------- Stage 2: FC routing ----------------
// 64 blocks, 1024 threads = 64 groups x 16 m-lanes (m<10 active for softmax).
__global__ __launch_bounds__(1024, 4) void fc_routing_kernel(
    const float* __restrict__ fcin,  // [64][1568][16]
    const float* __restrict__ wT2b,  // [1568][16][16] ([n][m][x*4+d], m padded)
    const float* __restrict__ ln2g,
    const float* __restrict__ ln2b,
    const int*   __restrict__ nroute,
    float* __restrict__ out)         // [64][10][16]
{
    __shared__ float s_u[16][20];
    __shared__ float s_red[15][16][20];

    const int b   = blockIdx.x;
    const int tid = threadIdx.x;
    const int ml  = tid & 15;     // m slot
    const int g   = tid >> 4;     // 0..63
    const int wvi = tid >> 6;     // 0..15
    const int R = *nroute;
    const float* fb = fcin + b * 1568 * 16;
    const int tmax = (g < 32) ? 25 : 24;   // wave-uniform

    for (int pass = 0; pass < R; ++pass) {
        float un[16];
#pragma unroll
        for (int i = 0; i < 16; ++i) un[i] = 0.f;
        float ur[16];
        if (pass) {
#pragma unroll
            for (int q = 0; q < 4; ++q)
                *(float4*)(&ur[q * 4]) = *(const float4*)(&s_u[ml][q * 4]);
        }

        float wA[16], inA[16];
        {
            const float* wp = wT2b + (g * 16 + ml) * 16;
            const float* ip = fb + g * 16;
#pragma unroll
            for (int q = 0; q < 4; ++q) {
                *(float4*)(&wA[q * 4]) = *(const float4*)(wp + q * 4);
                *(float4*)(&inA[q * 4]) = *(const float4*)(ip + q * 4);
            }
        }

        for (int t = 0; t < tmax; ++t) {
            float wv[16], iv[16];
#pragma unroll
            for (int i = 0; i < 16; ++i) { wv[i] = wA[i]; iv[i] = inA[i]; }
            if (t + 1 < tmax) {
                const int n2 = g + (t + 1) * 64;
                const float* wp = wT2b + (n2 * 16 + ml) * 16;
                const float* ip = fb + n2 * 16;
#pragma unroll
                for (int q = 0; q < 4; ++q) {
                    *(float4*)(&wA[q * 4]) = *(const float4*)(wp + q * 4);
                    *(float4*)(&inA[q * 4]) = *(const float4*)(ip + q * 4);
                }
            }
            float vote[16];
#pragma unroll
            for (int a = 0; a < 4; ++a) {
#pragma unroll
                for (int d = 0; d < 4; ++d) {
                    float acc = iv[a * 4 + 0] * wv[0 + d];
                    acc = fmaf(iv[a * 4 + 1], wv[4 + d], acc);
                    acc = fmaf(iv[a * 4 + 2], wv[8 + d], acc);
                    acc = fmaf(iv[a * 4 + 3], wv[12 + d], acc);
                    vote[a * 4 + d] = acc;
                }
            }
            if (pass == 0) {
#pragma unroll
                for (int i = 0; i < 16; ++i) un[i] += vote[i];
            } else {
                float lg = 0.f;
#pragma unroll
                for (int i = 0; i < 16; ++i) lg = fmaf(vote[i], ur[i], lg);
                lg *= 0.25f;
                float e = __expf(lg);
                if (ml >= 10) e = 0.f;
                float sm = e;
#pragma unroll
                for (int off = 8; off >= 1; off >>= 1)
                    sm += __shfl_xor(sm, off, 16);
                const float qk = e * __builtin_amdgcn_rcpf(sm * (1.f + 1e-10f));
#pragma unroll
                for (int i = 0; i < 16; ++i) un[i] = fmaf(qk, vote[i], un[i]);
            }
        }

        // reduce across the 4 groups of each wave
#pragma unroll
        for (int i = 0; i < 16; ++i) {
            un[i] += __shfl_xor(un[i], 16, 64);
            un[i] += __shfl_xor(un[i], 32, 64);
        }
        if (wvi > 0 && (tid & 63) < 16) {
#pragma unroll
            for (int q = 0; q < 4; ++q)
                *(float4*)(&s_red[wvi - 1][ml][q * 4]) = *(float4*)(&un[q * 4]);
        }
        __syncthreads();

        if (wvi == 0 && tid < 16) {
#pragma unroll
            for (int j = 0; j < 15; ++j) {
#pragma unroll
                for (int i = 0; i < 16; ++i) un[i] += s_red[j][ml][i];
            }
            const float scale = pass ? 1.f : 0.1f;
            float mu = 0.f;
#pragma unroll
            for (int i = 0; i < 16; ++i) { un[i] *= scale; mu += un[i]; }
            mu *= (1.f / 16.f);
            float var = 0.f;
#pragma unroll
            for (int i = 0; i < 16; ++i) {
                const float d0 = un[i] - mu;
                var = fmaf(d0, d0, var);
            }
            var *= (1.f / 16.f);
            const float inv = rsqrtf(var + LN_EPS);
#pragma unroll
            for (int i = 0; i < 16; ++i)
                s_u[ml][i] = (un[i] - mu) * inv * ln2g[i] + ln2b[i];
        }
        __syncthreads();
    }

    if (tid < 160) out[b * 160 + tid] = s_u[tid >> 4][tid & 15];
}

extern "C" void kernel_launch(void* const* d_in, const int* in_sizes, int n_in,
                              void* d_out, int out_size, void* d_ws, size_t ws_size,
                              hipStream_t stream) {
    const float* x     = (const float*)d_in[0];
    const float* wconv = (const float*)d_in[1];
    const float* wfc   = (const float*)d_in[2];
    const float* ln1g  = (const float*)d_in[3];
    const float* ln1b  = (const float*)d_in[4];
    const float* ln2g  = (const float*)d_in[5];
    const float* ln2b  = (const float*)d_in[6];
    const int*   nrt   = (const int*)d_in[7];

    float* vout = (float*)d_ws;                              // 6,422,528 B
    // wT (conv, 589,824 B) and wT2b (fc, 1,605,632 B) share this region:
    // transpose_wfc runs AFTER conv_routing_kernel has consumed wT.
    float* wT   = (float*)((char*)d_ws + 6422528);
    float* wT2b = (float*)((char*)d_ws + 6422528);
    float* out  = (float*)d_out;

    hipLaunchKernelGGL(transpose_wconv, dim3(576), dim3(256), 0, stream,
                       wconv, wT);
    hipLaunchKernelGGL(conv_routing_kernel, dim3(1568), dim3(256), 0, stream,
                       x, wT, ln1g, ln1b, nrt, vout);
    hipLaunchKernelGGL(transpose_wfc, dim3(1568), dim3(256), 0, stream,
                       wfc, wT2b);
    hipLaunchKernelGGL(fc_routing_kernel, dim3(64), dim3(1024), 0, stream,
                       vout, wT2b, ln2g, ln2b, nrt, out);
}

// Round 5
// 490.512 us; speedup vs baseline: 1.4284x; 1.0325x over previous
//
#include <hip/hip_runtime.h>
#include <hip/hip_bf16.h>

// CapsModel: B=64 N=32 H=W=16 A=16 K=3 stride=2 -> Ho=Wo=7, M=32, SD=4, D=16
// conv routing: 2 sites/block, 512 thr (site x 8 nkl-groups x 32 m-lanes),
//               ONE site per thread -> 64 persistent floats, no spills.
// fc routing:   pass-split kernels: partial (512 blocks) + combine/LN (64).
// No-max softmax (|logit| <~16, exp safe in fp32).

#define LN_EPS 1e-5f

// ---------------- weight transposes ----------------
// wT [288][32][16]: row r = n*9+kl (n-major, matches s_inp), wT[(r*32+m)*16+xd]
__global__ __launch_bounds__(256) void transpose_wconv(
    const float* __restrict__ wconv, float* __restrict__ wT)
{
    const int i = blockIdx.x * 256 + threadIdx.x;
    if (i < 147456) {
        const int xd = i & 15, mm = (i >> 4) & 31, r = i >> 9;   // r = n*9+kl
        const int n = r / 9, kl = r % 9;
        wT[i] = wconv[((kl * 32 + n) * 16 + xd) * 32 + mm];
    }
}

// wT2b [1568][16][16]: [n][m (pad 10->16, zeros)][x*4+d]
__global__ __launch_bounds__(256) void transpose_wfc(
    const float* __restrict__ wfc, float* __restrict__ wT2b)
{
    const int j = blockIdx.x * 256 + threadIdx.x;
    if (j < 401408) {
        const int xd = j & 15, mm = (j >> 4) & 15, n = j >> 8;
        const int x = xd >> 2, dd = xd & 3;
        wT2b[j] = (mm < 10) ? wfc[((n * 4 + x) * 4 + dd) * 10 + mm] : 0.f;
    }
}

// ---------------- Stage 1: conv routing ----------------
__global__ __launch_bounds__(512, 4) void conv_routing_kernel(
    const float* __restrict__ x,      // [64][32][16][16][16]
    const float* __restrict__ wT,     // [288][32][16], row = n*9+kl
    const float* __restrict__ ln1g,
    const float* __restrict__ ln1b,
    const int*   __restrict__ nroute,
    float* __restrict__ vout)         // [64][32][49][16]
{
    __shared__ float s_inp[2][288][16];     // 36 KB
    __shared__ float s_v[2][32][16];        // 4 KB
    __shared__ float s_red[3][2][32][16];   // 12 KB (waves 1..3 of each site)

    const int tid    = threadIdx.x;
    const int site_l = tid >> 8;            // 0/1
    const int m      = tid & 31;
    const int g      = (tid >> 5) & 7;      // 0..7
    const int lw     = (tid >> 6) & 3;      // wave within site
    const int hmask  = tid & 32;
    const int site0  = blockIdx.x * 2;

    // stage inp for both sites (float4, coalesced); row = n*9+kl
    for (int i = tid; i < 2304; i += 512) {
        const int s = (i >= 1152) ? 1 : 0;
        const int j = s ? i - 1152 : i;
        const int row = j >> 2, q = j & 3;
        const int site = site0 + s;
        const int b = site / 49, hw = site % 49;
        const int h = hw / 7, w = hw % 7;
        const int n = row / 9, kl = row % 9;
        const int k = kl / 3, l = kl % 3;
        const float4 val = *(const float4*)(
            x + ((((b * 32 + n) * 16 + (2 * h + k)) * 16 + (2 * w + l)) * 16 + q * 4));
        *(float4*)(&s_inp[s][row][q * 4]) = val;
    }
    __syncthreads();

    const int R = *nroute;
    const int nkl0 = g * 36;
    const float* const wp0 = wT + (nkl0 * 32 + m) * 16;

#define LDW(dst, p)                                                    \
    {                                                                  \
        _Pragma("unroll") for (int q = 0; q < 4; ++q)                  \
            *(float4*)(&(dst)[q * 4]) = *(const float4*)((p) + q * 4); \
    }

    for (int pass = 0; pass < R; ++pass) {
        float vn[16];
#pragma unroll
        for (int i = 0; i < 16; ++i) vn[i] = 0.f;
        float vc[16];
        if (pass) {
#pragma unroll
            for (int q = 0; q < 4; ++q)
                *(float4*)(&vc[q * 4]) = *(const float4*)(&s_v[site_l][m][q * 4]);
        }

        auto body0 = [&](int t, const float* wv) {
            const int nkl = nkl0 + t;
            float in_[16];
#pragma unroll
            for (int q = 0; q < 4; ++q)
                *(float4*)(&in_[q * 4]) = *(const float4*)(&s_inp[site_l][nkl][q * 4]);
#pragma unroll
            for (int a = 0; a < 4; ++a) {
#pragma unroll
                for (int d = 0; d < 4; ++d) {
                    float acc = in_[a * 4 + 0] * wv[0 + d];
                    acc = fmaf(in_[a * 4 + 1], wv[4 + d], acc);
                    acc = fmaf(in_[a * 4 + 2], wv[8 + d], acc);
                    acc = fmaf(in_[a * 4 + 3], wv[12 + d], acc);
                    vn[a * 4 + d] += acc;
                }
            }
        };

        auto body1 = [&](int t, const float* wv) {
            const int nkl = nkl0 + t;
            float in_[16];
#pragma unroll
            for (int q = 0; q < 4; ++q)
                *(float4*)(&in_[q * 4]) = *(const float4*)(&s_inp[site_l][nkl][q * 4]);
            float uh[16];
#pragma unroll
            for (int a = 0; a < 4; ++a) {
#pragma unroll
                for (int d = 0; d < 4; ++d) {
                    float acc = in_[a * 4 + 0] * wv[0 + d];
                    acc = fmaf(in_[a * 4 + 1], wv[4 + d], acc);
                    acc = fmaf(in_[a * 4 + 2], wv[8 + d], acc);
                    acc = fmaf(in_[a * 4 + 3], wv[12 + d], acc);
                    uh[a * 4 + d] = acc;
                }
            }
            float lg = 0.f;
#pragma unroll
            for (int i = 0; i < 16; ++i) lg = fmaf(uh[i], vc[i], lg);
            lg *= 0.25f;
            const float e = __expf(lg);
            float sm = e;
#pragma unroll
            for (int off = 16; off >= 1; off >>= 1)
                sm += __shfl_xor(sm, off, 32);
            const float qk = e * __builtin_amdgcn_rcpf(sm * (1.f + 1e-10f));
#pragma unroll
            for (int i = 0; i < 16; ++i) vn[i] = fmaf(qk, uh[i], vn[i]);
        };

        // K-loop, unroll 2 with double-buffered w prefetch
        {
            const float* wp = wp0;
            float wA[16], wB[16];
            LDW(wA, wp);
            if (pass == 0) {
                for (int t2 = 0; t2 < 18; ++t2) {
                    const int t = t2 * 2;
                    LDW(wB, wp + 512);
                    body0(t, wA);
                    if (t2 < 17) LDW(wA, wp + 1024);
                    body0(t + 1, wB);
                    wp += 1024;
                }
            } else {
                for (int t2 = 0; t2 < 18; ++t2) {
                    const int t = t2 * 2;
                    LDW(wB, wp + 512);
                    body1(t, wA);
                    if (t2 < 17) LDW(wA, wp + 1024);
                    body1(t + 1, wB);
                    wp += 1024;
                }
            }
        }

        // combine the 2 g's within each wave (both halves end with the pair-sum)
#pragma unroll
        for (int i = 0; i < 16; ++i) vn[i] += __shfl_xor(vn[i], 32, 64);

        if (lw > 0 && hmask == 0) {
#pragma unroll
            for (int q = 0; q < 4; ++q)
                *(float4*)(&s_red[lw - 1][site_l][m][q * 4]) = *(float4*)(&vn[q * 4]);
        }
        __syncthreads();

        if (lw == 0 && hmask == 0) {
#pragma unroll
            for (int j = 0; j < 3; ++j)
#pragma unroll
                for (int i = 0; i < 16; ++i) vn[i] += s_red[j][site_l][m][i];

            const float scale = pass ? 1.f : (1.f / 32.f);
            float mu = 0.f;
#pragma unroll
            for (int i = 0; i < 16; ++i) { vn[i] *= scale; mu += vn[i]; }
            mu *= (1.f / 16.f);
            float var = 0.f;
#pragma unroll
            for (int i = 0; i < 16; ++i) {
                const float d0 = vn[i] - mu;
                var = fmaf(d0, d0, var);
            }
            var *= (1.f / 16.f);
            const float inv = rsqrtf(var + LN_EPS);
#pragma unroll
            for (int i = 0; i < 16; ++i)
                s_v[site_l][m][i] = (vn[i] - mu) * inv * ln1g[i] + ln1b[i];
        }
        __syncthreads();
    }

    // write v: 256 float4
    if (tid < 256) {
        const int p = tid;
        const int s = p >> 7, mm = (p >> 2) & 31, q = p & 3;
        const int site = site0 + s;
        const int b = site / 49, hw = site % 49;
        const float4 val = *(const float4*)(&s_v[s][mm][q * 4]);
        *(float4*)(vout + ((b * 32 + mm) * 49 + hw) * 16 + q * 4) = val;
    }
}

// ---------------- Stage 2: FC routing (pass-split) ----------------
// fc_partial: 512 blocks = 64 b x 8 chunks; 256 thr = 16 grp x 16 ml.
// Chunk c covers n in [c*196, (c+1)*196); within it n = base + t*16 + grp.
__global__ __launch_bounds__(256, 4) void fc_partial(
    const float* __restrict__ fcin,  // [64][1568][16]
    const float* __restrict__ wT2b,  // [1568][16][16] ([n][ml][x*4+d])
    const float* __restrict__ u,     // [64][16][16] ([b][ml][ad])
    const int*   __restrict__ nroute,
    const int    pass,
    float* __restrict__ partial)     // [512][16][16]
{
    __shared__ float s_red[4][16][17];

    const int R = *nroute;
    if (pass >= R) return;
    const int blk = blockIdx.x;
    const int b = blk >> 3, c = blk & 7;
    const int tid = threadIdx.x;
    const int ml = tid & 15, grp = tid >> 4;   // grp 0..15
    const int wv = tid >> 6;
    const float* fb = fcin + (b * 1568 + c * 196) * 16;
    const float* wb = wT2b + (c * 196 * 16) * 16;

    float un[16];
#pragma unroll
    for (int i = 0; i < 16; ++i) un[i] = 0.f;
    float ur[16];
    if (pass) {
#pragma unroll
        for (int q = 0; q < 4; ++q)
            *(float4*)(&ur[q * 4]) = *(const float4*)(u + (b * 16 + ml) * 16 + q * 4);
    }

    for (int t = 0; t < 13; ++t) {
        const int off = t * 16 + grp;
        if (off >= 196) break;   // uniform within each 16-lane cluster
        float iv[16], wv_[16];
        const float* ip = fb + off * 16;
        const float* wp = wb + (off * 16 + ml) * 16;
#pragma unroll
        for (int q = 0; q < 4; ++q) {
            *(float4*)(&iv[q * 4]) = *(const float4*)(ip + q * 4);
            *(float4*)(&wv_[q * 4]) = *(const float4*)(wp + q * 4);
        }
        float vote[16];
#pragma unroll
        for (int a = 0; a < 4; ++a) {
#pragma unroll
            for (int d = 0; d < 4; ++d) {
                float acc = iv[a * 4 + 0] * wv_[0 + d];
                acc = fmaf(iv[a * 4 + 1], wv_[4 + d], acc);
                acc = fmaf(iv[a * 4 + 2], wv_[8 + d], acc);
                acc = fmaf(iv[a * 4 + 3], wv_[12 + d], acc);
                vote[a * 4 + d] = acc;
            }
        }
        if (pass == 0) {
#pragma unroll
            for (int i = 0; i < 16; ++i) un[i] += vote[i];
        } else {
            float lg = 0.f;
#pragma unroll
            for (int i = 0; i < 16; ++i) lg = fmaf(vote[i], ur[i], lg);
            lg *= 0.25f;
            float e = __expf(lg);
            if (ml >= 10) e = 0.f;
            float sm = e;
#pragma unroll
            for (int off2 = 8; off2 >= 1; off2 >>= 1)
                sm += __shfl_xor(sm, off2, 16);
            const float qk = e * __builtin_amdgcn_rcpf(sm * (1.f + 1e-10f));
#pragma unroll
            for (int i = 0; i < 16; ++i) un[i] = fmaf(qk, vote[i], un[i]);
        }
    }

    // sum the 4 grps within each wave
#pragma unroll
    for (int i = 0; i < 16; ++i) {
        un[i] += __shfl_xor(un[i], 16, 64);
        un[i] += __shfl_xor(un[i], 32, 64);
    }
    if ((tid & 63) < 16) {
#pragma unroll
        for (int i = 0; i < 16; ++i) s_red[wv][ml][i] = un[i];
    }
    __syncthreads();

    // 256 threads: (mlf, i) -> sum 4 waves, write partial
    {
        const int mlf = tid >> 4, i = tid & 15;
        const float s = s_red[0][mlf][i] + s_red[1][mlf][i]
                      + s_red[2][mlf][i] + s_red[3][mlf][i];
        partial[(blk * 16 + mlf) * 16 + i] = s;
    }
}

// fc_combine: 64 blocks x 256 thr; thread = (ml = tid>>4, i = tid&15).
__global__ __launch_bounds__(256) void fc_combine(
    const float* __restrict__ partial,  // [512][16][16]
    const float* __restrict__ ln2g,
    const float* __restrict__ ln2b,
    const int*   __restrict__ nroute,
    const int    pass,
    float* __restrict__ u,              // [64][16][16]
    float* __restrict__ out)            // [64][10][16]
{
    const int R = *nroute;
    if (pass >= R) return;
    const int b = blockIdx.x;
    const int tid = threadIdx.x;
    const int i = tid & 15, ml = tid >> 4;

    float s = 0.f;
#pragma unroll
    for (int c = 0; c < 8; ++c)
        s += partial[((b * 8 + c) * 16 + ml) * 16 + i];
    if (pass == 0) s *= 0.1f;

    // LN over the 16 i-lanes of this cluster
    float mu = s;
#pragma unroll
    for (int off = 8; off >= 1; off >>= 1) mu += __shfl_xor(mu, off, 16);
    mu *= (1.f / 16.f);
    const float d0 = s - mu;
    float var = d0 * d0;
#pragma unroll
    for (int off = 8; off >= 1; off >>= 1) var += __shfl_xor(var, off, 16);
    var *= (1.f / 16.f);
    const float r = (s - mu) * rsqrtf(var + LN_EPS) * ln2g[i] + ln2b[i];

    u[(b * 16 + ml) * 16 + i] = r;
    if (pass == R - 1 && ml < 10) out[(b * 10 + ml) * 16 + i] = r;
}

extern "C" void kernel_launch(void* const* d_in, const int* in_sizes, int n_in,
                              void* d_out, int out_size, void* d_ws, size_t ws_size,
                              hipStream_t stream) {
    const float* x     = (const float*)d_in[0];
    const float* wconv = (const float*)d_in[1];
    const float* wfc   = (const float*)d_in[2];
    const float* ln1g  = (const float*)d_in[3];
    const float* ln1b  = (const float*)d_in[4];
    const float* ln2g  = (const float*)d_in[5];
    const float* ln2b  = (const float*)d_in[6];
    const int*   nrt   = (const int*)d_in[7];

    float* vout    = (float*)d_ws;                               // 6,422,528 B
    // wT (589,824 B) and wT2b (1,605,632 B) share this region (sequenced).
    float* wT      = (float*)((char*)d_ws + 6422528);
    float* wT2b    = (float*)((char*)d_ws + 6422528);
    float* ubuf    = (float*)((char*)d_ws + 8028160);            // 65,536 B
    float* partial = (float*)((char*)d_ws + 8093696);            // 524,288 B
    float* out     = (float*)d_out;

    hipLaunchKernelGGL(transpose_wconv, dim3(576), dim3(256), 0, stream,
                       wconv, wT);
    hipLaunchKernelGGL(conv_routing_kernel, dim3(1568), dim3(512), 0, stream,
                       x, wT, ln1g, ln1b, nrt, vout);
    hipLaunchKernelGGL(transpose_wfc, dim3(1568), dim3(256), 0, stream,
                       wfc, wT2b);
    for (int pass = 0; pass < 3; ++pass) {
        hipLaunchKernelGGL(fc_partial, dim3(512), dim3(256), 0, stream,
                           vout, wT2b, ubuf, nrt, pass, partial);
        hipLaunchKernelGGL(fc_combine, dim3(64), dim3(256), 0, stream,
                           partial, ln2g, ln2b, nrt, pass, ubuf, out);
    }
}